// Round 2
// baseline (102.333 us; speedup 1.0000x reference)
//
#include <hip/hip_runtime.h>
#include <cstdint>

// PillarVFE fused kernel (float32 in / float32 out), MI355X gfx950.
//
// Inputs (setup_inputs order, all reference dtypes):
//   0: voxels        [P][32][4]  f32
//   1: W             [64][9]     f32
//   2: gamma         [64]        f32
//   3: beta          [64]        f32
//   4: running_mean  [64]        f32
//   5: running_var   [64]        f32
//   6: voxel_num_points [P]      int32
//   7: voxel_coords  [P][4]      int32
// Output: [P][64] f32
//
// Algebra: bn(conv(feats))[o] is affine in the raw point (v0,v1,v2,v3):
//   acc = v0*A0 + v1*A1 + v2*A2 + v3*A3 + C
//   A0=(w0+w4+w7)*s, A1=(w1+w5+w8)*s, A2=(w2+w6)*s, A3=w3*s
//   C = beta - mean*s - (cx*(w0+w7) + cy*(w1+w8) + mx*w4 + my*w5 + mz*w6)*s
// Masked rows (n>=npts) all equal relu(beta - mean*s): seed the max with it
// when npts<32 and loop only n<npts.

__global__ __launch_bounds__(256) void pillar_vfe_kernel(
    const float2* __restrict__ voxels2,   // [P*128] float2 (= [P][32][4] f32)
    const float*  __restrict__ Wp,        // [64][9]
    const float*  __restrict__ gamma_p,
    const float*  __restrict__ beta_p,
    const float*  __restrict__ rmean_p,
    const float*  __restrict__ rvar_p,
    const int*    __restrict__ npts_p,    // [P]
    const int*    __restrict__ coords_p,  // [P][4]
    float*        __restrict__ out,       // [P][64]
    int P)
{
    __shared__ float2 sh[4 * 64];         // 4 pillars x 32 pts x 16B

    const int tid    = threadIdx.x;
    const int pblock = blockIdx.x * 4;

    // cooperative stage: 256 float2 (4 pillars of voxel data)
    {
        const int gidx = pblock * 64 + tid;   // float2 index
        if (gidx < P * 64) sh[tid] = voxels2[gidx];
    }
    __syncthreads();

    const int wave = tid >> 6;
    const int lane = tid & 63;
    const int p    = pblock + wave;
    if (p >= P) return;

    // ---- per-pillar scalars (wave-uniform) ----
    const int   npts = npts_p[p];
    const float fn   = (float)npts;
    const float cx   = (float)coords_p[p * 4 + 3] * 0.16f + 0.08f;
    const float cy   = (float)coords_p[p * 4 + 2] * 0.16f + (0.08f - 39.68f);

    // cluster mean: sum xyz over ALL 32 points (reference semantics), / npts
    const float2* shp = sh + wave * 64;   // 64 float2 = 32 points
    float sx = 0.f, sy = 0.f, sz = 0.f;
    if (lane < 32) {
        const float2 a = shp[lane * 2];       // (x, y)
        const float2 b = shp[lane * 2 + 1];   // (z, w)
        sx = a.x; sy = a.y; sz = b.x;
    }
    #pragma unroll
    for (int m = 16; m >= 1; m >>= 1) {
        sx += __shfl_xor(sx, m, 64);
        sy += __shfl_xor(sy, m, 64);
        sz += __shfl_xor(sz, m, 64);
    }
    sx = __shfl(sx, 0, 64);
    sy = __shfl(sy, 0, 64);
    sz = __shfl(sz, 0, 64);
    const float mx = sx / fn, my = sy / fn, mz = sz / fn;

    // ---- per-channel (lane) params ----
    const int o = lane;
    float w[9];
    #pragma unroll
    for (int c = 0; c < 9; ++c) w[c] = Wp[o * 9 + c];
    const float g     = gamma_p[o];
    const float b     = beta_p[o];
    const float mu    = rmean_p[o];
    const float var   = rvar_p[o];
    const float scale = g / sqrtf(var + 1e-3f);

    const float A0 = (w[0] + w[4] + w[7]) * scale;
    const float A1 = (w[1] + w[5] + w[8]) * scale;
    const float A2 = (w[2] + w[6]) * scale;
    const float A3 = w[3] * scale;
    const float C0 = b - mu * scale;              // masked-row value (pre-relu)
    const float C  = C0 - (cx * (w[0] + w[7]) + cy * (w[1] + w[8])
                           + mx * w[4] + my * w[5] + mz * w[6]) * scale;

    float vmax = (npts < 32) ? fmaxf(C0, 0.0f) : -3.4e38f;

    for (int n = 0; n < npts; ++n) {
        const float2 a  = shp[n * 2];
        const float2 bu = shp[n * 2 + 1];
        float acc = C;
        acc = fmaf(a.x,  A0, acc);
        acc = fmaf(a.y,  A1, acc);
        acc = fmaf(bu.x, A2, acc);
        acc = fmaf(bu.y, A3, acc);
        vmax = fmaxf(vmax, acc);
    }
    // reference applies relu BEFORE max; since masked-row constant already
    // relu'd into the seed when npts<32, and for npts==32 all rows are real:
    vmax = fmaxf(vmax, 0.0f) * 0.0f + fmaxf(vmax, 0.0f);  // placeholder-free relu
    // (relu(max(x_i)) == max(relu(x_i)) for nonempty set)
    vmax = fmaxf(vmax, 0.0f);

    out[p * 64 + o] = vmax;
}

extern "C" void kernel_launch(void* const* d_in, const int* in_sizes, int n_in,
                              void* d_out, int out_size, void* d_ws, size_t ws_size,
                              hipStream_t stream) {
    const float2* voxels = (const float2*)d_in[0];
    const float*  W      = (const float*)d_in[1];
    const float*  gamma_ = (const float*)d_in[2];
    const float*  beta_  = (const float*)d_in[3];
    const float*  rmean  = (const float*)d_in[4];
    const float*  rvar   = (const float*)d_in[5];
    const int*    npts   = (const int*)d_in[6];
    const int*    coords = (const int*)d_in[7];
    float*        out    = (float*)d_out;

    const int P = in_sizes[6];           // 40000
    const int blocks = (P + 3) / 4;      // 4 pillars / block (1 wave each)

    pillar_vfe_kernel<<<blocks, 256, 0, stream>>>(
        voxels, W, gamma_, beta_, rmean, rvar, npts, coords, out, P);
}

// Round 3
// 100.522 us; speedup vs baseline: 1.0180x; 1.0180x over previous
//
#include <hip/hip_runtime.h>
#include <cstdint>

// PillarVFE fused (f32 in / f32 out), MI355X gfx950.
//
// Inputs: 0 voxels [P][32][4] f32 | 1 W [64][9] | 2 gamma [64] | 3 beta [64]
//         4 running_mean [64] | 5 running_var [64] | 6 voxel_num_points [P] i32
//         7 voxel_coords [P][4] i32.  Output: [P][64] f32.
//
// bn(conv(feats))[o] is affine in the raw point (v0,v1,v2,v3):
//   acc_n = v0*A0 + v1*A1 + v2*A2 + v3*A3 + C0 - cx*SW07 - cy*SW18 - meanterm
//   A0=(w0+w4+w7)s  A1=(w1+w5+w8)s  A2=(w2+w6)s  A3=w3*s
//   C0=beta-mean*s  SW07=(w0+w7)s  SW18=(w1+w8)s  meanterm=mx*w4*s+my*w5*s+mz*w6*s
// meanterm is constant over n, so it is subtracted AFTER the max (exact).
// Masked rows (n>=npts) evaluate to C0 exactly (feats==0) — seed separately.
//
// Kernel 1 precomputes the 10 per-channel constants into d_ws (coalesced
// [10][64] layout) so the main kernel never does strided W reads.

__global__ __launch_bounds__(64) void pillar_setup_kernel(
    const float* __restrict__ Wp,      // [64][9]
    const float* __restrict__ gamma_p,
    const float* __restrict__ beta_p,
    const float* __restrict__ rmean_p,
    const float* __restrict__ rvar_p,
    float*       __restrict__ params)  // [10][64]
{
    const int o = threadIdx.x;         // channel 0..63
    float w[9];
    #pragma unroll
    for (int c = 0; c < 9; ++c) w[c] = Wp[o * 9 + c];
    const float s = gamma_p[o] / sqrtf(rvar_p[o] + 1e-3f);

    params[0 * 64 + o] = (w[0] + w[4] + w[7]) * s;   // A0
    params[1 * 64 + o] = (w[1] + w[5] + w[8]) * s;   // A1
    params[2 * 64 + o] = (w[2] + w[6]) * s;          // A2
    params[3 * 64 + o] = w[3] * s;                   // A3
    params[4 * 64 + o] = beta_p[o] - rmean_p[o] * s; // C0
    params[5 * 64 + o] = (w[0] + w[7]) * s;          // SW07 (cx coeff)
    params[6 * 64 + o] = (w[1] + w[8]) * s;          // SW18 (cy coeff)
    params[7 * 64 + o] = w[4] * s;                   // SW4 (mx coeff)
    params[8 * 64 + o] = w[5] * s;                   // SW5 (my coeff)
    params[9 * 64 + o] = w[6] * s;                   // SW6 (mz coeff)
}

__global__ __launch_bounds__(256) void pillar_vfe_kernel(
    const float4* __restrict__ voxels4,   // [P*32] float4
    const float*  __restrict__ params,    // [10][64]
    const int*    __restrict__ npts_p,    // [P]
    const int*    __restrict__ coords_p,  // [P][4]
    float*        __restrict__ out,       // [P][64]
    int P)
{
    __shared__ float4 sh[4 * 32];         // 4 pillars x 32 points

    const int tid    = threadIdx.x;
    const int pblock = blockIdx.x * 4;

    // cooperative stage: 128 float4 by threads 0..127 (coalesced 2 KB)
    if (tid < 128) {
        const int gidx = pblock * 32 + tid;
        if (gidx < P * 32) sh[tid] = voxels4[gidx];
    }
    __syncthreads();

    const int wave = tid >> 6;
    const int lane = tid & 63;
    const int p    = pblock + wave;
    if (p >= P) return;

    // per-channel folded constants (coalesced, L1-resident)
    const float A0   = params[0 * 64 + lane];
    const float A1   = params[1 * 64 + lane];
    const float A2   = params[2 * 64 + lane];
    const float A3   = params[3 * 64 + lane];
    const float C0   = params[4 * 64 + lane];
    const float SW07 = params[5 * 64 + lane];
    const float SW18 = params[6 * 64 + lane];
    const float SW4  = params[7 * 64 + lane];
    const float SW5  = params[8 * 64 + lane];
    const float SW6  = params[9 * 64 + lane];

    const int   npts = npts_p[p];
    const float fn   = (float)npts;
    const float cx   = (float)coords_p[p * 4 + 3] * 0.16f + 0.08f;
    const float cy   = (float)coords_p[p * 4 + 2] * 0.16f + (0.08f - 39.68f);

    const float4* shp = sh + wave * 32;

    // xyz sums over all 32 points (reference semantics) — butterfly over all
    // 64 lanes (high 32 contribute 0) so every lane ends with the full sum.
    float sx = 0.f, sy = 0.f, sz = 0.f;
    if (lane < 32) {
        const float4 v = shp[lane];
        sx = v.x; sy = v.y; sz = v.z;
    }
    #pragma unroll
    for (int m = 32; m >= 1; m >>= 1) {
        sx += __shfl_xor(sx, m, 64);
        sy += __shfl_xor(sy, m, 64);
        sz += __shfl_xor(sz, m, 64);
    }

    // point loop: independent of the mean (deferred subtraction)
    const float C1 = C0 - cx * SW07 - cy * SW18;
    float vmax = -3.4e38f;
    for (int n = 0; n < npts; ++n) {
        const float4 v = shp[n];
        float acc = C1;
        acc  = fmaf(v.x, A0, acc);
        acc  = fmaf(v.y, A1, acc);
        acc  = fmaf(v.z, A2, acc);
        acc  = fmaf(v.w, A3, acc);
        vmax = fmaxf(vmax, acc);
    }

    const float inv_n    = 1.0f / fn;
    const float meanterm = (sx * SW4 + sy * SW5 + sz * SW6) * inv_n;
    vmax -= meanterm;
    if (npts < 32) vmax = fmaxf(vmax, C0);   // masked rows contribute C0
    out[p * 64 + lane] = fmaxf(vmax, 0.0f);  // relu(max) == max(relu) here
}

extern "C" void kernel_launch(void* const* d_in, const int* in_sizes, int n_in,
                              void* d_out, int out_size, void* d_ws, size_t ws_size,
                              hipStream_t stream) {
    const float4* voxels = (const float4*)d_in[0];
    const float*  W      = (const float*)d_in[1];
    const float*  gamma_ = (const float*)d_in[2];
    const float*  beta_  = (const float*)d_in[3];
    const float*  rmean  = (const float*)d_in[4];
    const float*  rvar   = (const float*)d_in[5];
    const int*    npts   = (const int*)d_in[6];
    const int*    coords = (const int*)d_in[7];
    float*        out    = (float*)d_out;
    float*        params = (float*)d_ws;     // 640 floats

    const int P = in_sizes[6];               // 40000

    pillar_setup_kernel<<<1, 64, 0, stream>>>(W, gamma_, beta_, rmean, rvar, params);

    const int blocks = (P + 3) / 4;          // 4 pillars / block (1 wave each)
    pillar_vfe_kernel<<<blocks, 256, 0, stream>>>(voxels, params, npts, coords, out, P);
}